// Round 8
// baseline (176.559 us; speedup 1.0000x reference)
//
#include <hip/hip_runtime.h>
#include <hip/hip_bf16.h>

typedef unsigned short u16;
typedef __attribute__((ext_vector_type(8))) short bf16x8;   // 8 bf16 = 4 VGPRs
typedef __attribute__((ext_vector_type(4))) short bf16x4;
typedef __attribute__((ext_vector_type(4))) float f32x4;
typedef __attribute__((ext_vector_type(16))) float f32x16;

#define NBG   5000
#define NPID  5532
#define NTOT  15532      // 5000 + 5532 + 5000
#define FEAT  256
#define BATCH 4096
#define SCALE_LOG2E 43.280851226668994f   // 30 * log2(e)
#define LPITCH 264       // f32-fallback LDS pitch (shorts)

#define NTILE_B  976             // 61 chunks x 16 tiles; 971 real, 5 zero-pad
#define TILE_SH  4096            // shorts per 16-col tile (16*256)
#define NTILE_A  256             // 4096 rows / 16
#define STEP_SH  8192            // shorts per 32-col step (2 tiles)

// ---- workspace layout (bytes) ----
#define TABT_BYTES ((size_t)NTILE_B * TILE_SH * 2)   // 7,995,392
#define AT_BYTES   ((size_t)NTILE_A * TILE_SH * 2)   // 2,097,152
#define SUMS_OFF   (TABT_BYTES + AT_BYTES)
// S floats: [0,4096) bg | [4096,8192) nb | 8192 det | 8193 oim | 8194 nv | 8195 ticket
#define SUMS_FLOATS 8196
#define WS_NEED    (SUMS_OFF + SUMS_FLOATS * 4)

// raw v_exp_f32: args are in [-43.3, 43.3] -> no denorm/overflow fixups needed
__device__ __forceinline__ float fexp2(float x) {
#if __has_builtin(__builtin_amdgcn_exp2f)
    return __builtin_amdgcn_exp2f(x);
#else
    return exp2f(x);
#endif
}

__device__ __forceinline__ void atomic_add_f(float* p, float v) {
    __hip_atomic_fetch_add(p, v, __ATOMIC_RELAXED, __HIP_MEMORY_SCOPE_AGENT);
}
__device__ __forceinline__ short f2bf(float f) {
    return (short)__bfloat16_as_ushort(__float2bfloat16(f));
}
// bank-conflict swizzle: q-slot XORed with row/col bits 1..2.
__device__ __forceinline__ int swz(int rc, int q) { return q ^ ((rc >> 1) & 3); }

__device__ __forceinline__ const float* table_row(
    int n, const float* __restrict__ lut, const float* __restrict__ cq,
    const float* __restrict__ cqb)
{
    const int nc = n < NTOT ? n : NTOT - 1;
    if (nc < NBG)        return cqb + (size_t)nc * FEAT;
    if (nc < NBG + NPID) return lut + (size_t)(nc - NBG) * FEAT;
    return cq + (size_t)(nc - NBG - NPID) * FEAT;
}

// -------- Stage 0: f32 -> bf16 tiled prepass (table + inputs) + zero sums --
// Tile format (8192 B per 16-col tile): short off = kk*512 + col*32 + swz(col,q)*8
// holding src[col][kk*32 + q*8 .. +8]. Table rows are PRE-SCALED by 30*log2e
// so the score kernel's exp argument is the raw MFMA accumulator (no mul).
#define TAB_UNITS (NTILE_B * 512)    // 499,712
#define A_UNITS   (NTILE_A * 512)    // 131,072
#define PRE_BLOCKS ((TAB_UNITS + A_UNITS) / 256)   // 2464

__global__ __launch_bounds__(256) void prepass_kernel(
    const float* __restrict__ inputs, const float* __restrict__ lut,
    const float* __restrict__ cq, const float* __restrict__ cqb,
    u16* __restrict__ tabt, u16* __restrict__ at, float* __restrict__ S)
{
    const int u = blockIdx.x * 256 + threadIdx.x;
    if (u < SUMS_FLOATS) S[u] = 0.f;

    if (u < TAB_UNITS) {
        const int tile = u >> 9, v = u & 511;
        const int kk = v >> 6, col = (v >> 2) & 15, q = v & 3;
        const int cg = tile * 16 + col;
        bf16x8 r = {0, 0, 0, 0, 0, 0, 0, 0};
        if (cg < NTOT) {
            const float* src = table_row(cg, lut, cq, cqb) + kk * 32 + q * 8;
            const f32x4 lo = *(const f32x4*)src;
            const f32x4 hi = *(const f32x4*)(src + 4);
            r = bf16x8{ f2bf(lo[0] * SCALE_LOG2E), f2bf(lo[1] * SCALE_LOG2E),
                        f2bf(lo[2] * SCALE_LOG2E), f2bf(lo[3] * SCALE_LOG2E),
                        f2bf(hi[0] * SCALE_LOG2E), f2bf(hi[1] * SCALE_LOG2E),
                        f2bf(hi[2] * SCALE_LOG2E), f2bf(hi[3] * SCALE_LOG2E) };
        }
        const size_t off = (size_t)tile * TILE_SH + kk * 512 + col * 32 + swz(col, q) * 8;
        *(bf16x8*)(tabt + off) = r;
    } else {
        const int ua = u - TAB_UNITS;
        const int tile = ua >> 9, v = ua & 511;
        const int kk = v >> 6, row = (v >> 2) & 15, q = v & 3;
        const float* src = inputs + (size_t)(tile * 16 + row) * FEAT + kk * 32 + q * 8;
        const f32x4 lo = *(const f32x4*)src;
        const f32x4 hi = *(const f32x4*)(src + 4);
        bf16x8 r = { f2bf(lo[0]), f2bf(lo[1]), f2bf(lo[2]), f2bf(lo[3]),
                     f2bf(hi[0]), f2bf(hi[1]), f2bf(hi[2]), f2bf(hi[3]) };
        const size_t off = (size_t)tile * TILE_SH + kk * 512 + row * 32 + swz(row, q) * 8;
        *(bf16x8*)(at + off) = r;
    }
}

// -------- Stage 1: fused GEMM + exp-sum, LDS-shared B ----------------------
// 976 blocks (16 rowchunks x 61 colchunks), XCD-swizzled. 8 waves x 512 thr,
// block tile 256x256; wave owns 32 rows. NEW: v_mfma_f32_32x32x16_bf16 —
// per wave-step 16 MFMAs (was 32 of 16x16x32) for the same FLOPs: -17%
// matrix-pipe cycles (8.07cy/32.7KF vs 4.85/16.4KF), half the issue slots,
// same LDS bytes. Operand k-ordering is self-canceling (any per-lane k
// relabeling applied to BOTH A and B gives the same dot), so the existing
// swizzled tile format serves the fragments unchanged:
//   lane l, MFMA ks: A/B bf16x8 at kk=ks>>1, within-tile row/col = l&15,
//   tile = (l>>4)&1, q = (ks&1)*2 + (l>>5).
// C/D layout (verified m74/m101): col=lane&31, row=(reg&3)+8*(reg>>2)+4*(l>>5).
// Staging/barrier structure identical to the passing round-7 kernel:
// global_load_lds DMA, __syncthreads per step, prefetch after barrier.
__global__ __launch_bounds__(512, 4)
void score_bf16_kernel(
    const u16* __restrict__ tabt, const u16* __restrict__ at,
    float* __restrict__ sum_bg, float* __restrict__ sum_nb)
{
    __shared__ __align__(16) short lbuf[2][STEP_SH];
    const int lid = blockIdx.x;
    const int x8  = lid & 7;
    const int j   = lid >> 3;                 // [0, 122)
    const int rowchunk = x8 * 2 + (j & 1);    // [0, 16)
    const int colchunk = j >> 1;              // [0, 61)

    const int tid  = threadIdx.x;             // [0, 512)
    const int wave = tid >> 6;                // [0, 8)
    const int lane = tid & 63;
    const int col5 = lane & 31;               // MFMA col (B) / row (A) selector
    const int half = lane >> 5;               // k-group selector
    const int l15  = lane & 15;
    const int tsel = (lane >> 4) & 1;         // 16-wide tile within 32-col step
    // within-kk-block short offsets for the two q slots this lane uses:
    const int s0 = l15 * 32 + swz(l15, half) * 8;        // ks even: q = half
    const int s1 = l15 * 32 + swz(l15, 2 + half) * 8;    // ks odd:  q = 2+half

    const int steps = (colchunk == 60) ? 6 : 8;
    const u16* gbase = tabt + (size_t)colchunk * 16 * TILE_SH;

    // stage step t into buf: 512 threads x 32 B = 16 KB. Per wave: two 1 KB
    // DMAs (wave-uniform LDS base + lane*16B; format-preserving linear copy).
    const int stage_off = wave * 512 + lane * 8;      // shorts
    #define STAGE(buf_, t_)                                                    \
        {                                                                      \
            const u16* gs = gbase + (size_t)(t_) * STEP_SH + stage_off;        \
            short* ls = &lbuf[buf_][wave * 512];                               \
            __builtin_amdgcn_global_load_lds(                                  \
                (const __attribute__((address_space(1))) void*)(gs),           \
                (__attribute__((address_space(3))) void*)(ls), 16, 0, 0);      \
            __builtin_amdgcn_global_load_lds(                                  \
                (const __attribute__((address_space(1))) void*)(gs + 4096),    \
                (__attribute__((address_space(3))) void*)(ls + 4096), 16, 0, 0); \
        }

    // issue loads(0) first so they fly during the A-frag prologue
    STAGE(0, 0);

    // A fragments: wave rows [rowchunk*256 + wave*32, +32); lane row = col5.
    // af[ks] = A[row][ks*16 + half*8 .. +8] in the swizzled tile format.
    bf16x8 af[16];
    {
        const u16* ab = at + (size_t)(rowchunk * 16 + wave * 2 + tsel) * TILE_SH;
        #pragma unroll
        for (int ks = 0; ks < 16; ++ks)
            af[ks] = *(const bf16x8*)(ab + (ks >> 1) * 512 + ((ks & 1) ? s1 : s0));
    }

    float pbg[16], pnb[16];
    #pragma unroll
    for (int i = 0; i < 16; ++i) { pbg[i] = 0.f; pnb[i] = 0.f; }

    #pragma unroll 1
    for (int t = 0; t < steps; ++t) {
        __syncthreads();                       // drains loads(t); all waves synced
        if (t + 1 < steps) STAGE((t + 1) & 1, t + 1);   // prefetch under compute

        const short* lb = lbuf[t & 1] + tsel * TILE_SH;
        f32x16 acc = {};
        __builtin_amdgcn_s_setprio(1);         // T5: favor MFMA-issuing wave
        #pragma unroll
        for (int ks = 0; ks < 16; ++ks) {
            const bf16x8 b = *(const bf16x8*)(lb + (ks >> 1) * 512 + ((ks & 1) ? s1 : s0));
            acc = __builtin_amdgcn_mfma_f32_32x32x16_bf16(af[ks], b, acc, 0, 0, 0);
        }
        __builtin_amdgcn_s_setprio(0);

        const int cbase = colchunk * 256 + t * 32;   // global col of col5==0
        if (colchunk == 60) {                  // tail: mask pad cols
            const bool okc = (cbase + col5) < NTOT;
            #pragma unroll
            for (int i = 0; i < 16; ++i)
                pnb[i] += okc ? fexp2(acc[i]) : 0.f;
        } else if (cbase + 32 <= NBG) {        // all background
            #pragma unroll
            for (int i = 0; i < 16; ++i)
                pbg[i] += fexp2(acc[i]);
        } else if (cbase >= NBG) {             // all non-bg
            #pragma unroll
            for (int i = 0; i < 16; ++i)
                pnb[i] += fexp2(acc[i]);
        } else {                               // cbase==4992: split at col 5000
            const bool isbg = col5 < (NBG - cbase);
            #pragma unroll
            for (int i = 0; i < 16; ++i) {
                const float e = fexp2(acc[i]);
                pbg[i] += isbg ? e : 0.f;
                pnb[i] += isbg ? 0.f : e;
            }
        }
    }

    // reduce across the 32 cols (lanes within each 32-lane group)
    #pragma unroll
    for (int off = 1; off < 32; off <<= 1) {
        #pragma unroll
        for (int i = 0; i < 16; ++i) {
            pbg[i] += __shfl_xor(pbg[i], off);
            pnb[i] += __shfl_xor(pnb[i], off);
        }
    }
    if (col5 == 0) {
        #pragma unroll
        for (int reg = 0; reg < 16; ++reg) {
            const int row = rowchunk * 256 + wave * 32
                          + (reg & 3) + 8 * (reg >> 2) + 4 * half;
            atomic_add_f(&sum_bg[row], pbg[reg]);
            atomic_add_f(&sum_nb[row], pnb[reg]);
        }
    }
    #undef STAGE
}

// -------- Stage 1 (f32 fallback, round-4 structure, proven) ----------------
__global__ __launch_bounds__(256, 2) void score_f32_kernel(
    const float* __restrict__ inputs, const float* __restrict__ lut,
    const float* __restrict__ cq, const float* __restrict__ cqb,
    float* __restrict__ sum_bg, float* __restrict__ sum_nb)
{
    __shared__ __align__(16) short lds[32 * LPITCH];
    const int wave = threadIdx.x >> 6;
    const int lane = threadIdx.x & 63;
    const int l15  = lane & 15;
    const int quad = lane >> 4;
    const int rowbase = blockIdx.y * 256;
    const int colbase = blockIdx.x * 256;

    bf16x8 afrag[4][8];
    #pragma unroll 1
    for (int c = 0; c < 8; ++c) {
        __syncthreads();
        #pragma unroll
        for (int i = 0; i < 8; ++i) {
            const int lr = i * 4 + wave;
            const f32x4 v = *(const f32x4*)(inputs + (size_t)(rowbase + c * 32 + lr) * FEAT + lane * 4);
            bf16x4 h = { f2bf(v[0]), f2bf(v[1]), f2bf(v[2]), f2bf(v[3]) };
            *(bf16x4*)(&lds[lr * LPITCH + lane * 4]) = h;
        }
        __syncthreads();
        if ((c >> 1) == wave) {
            const int half = c & 1;
            #pragma unroll
            for (int j2 = 0; j2 < 2; ++j2) {
                const int lr = j2 * 16 + l15;
                #pragma unroll
                for (int kk = 0; kk < 8; ++kk)
                    afrag[half * 2 + j2][kk] =
                        *(const bf16x8*)(&lds[lr * LPITCH + kk * 32 + quad * 8]);
            }
        }
    }

    float pbg[16], pnb[16];
    #pragma unroll
    for (int i = 0; i < 16; ++i) { pbg[i] = 0.f; pnb[i] = 0.f; }

    #pragma unroll 1
    for (int s = 0; s < 8; ++s) {
        __syncthreads();
        #pragma unroll
        for (int i = 0; i < 8; ++i) {
            const int lc = i * 4 + wave;
            const f32x4 v = *(const f32x4*)(table_row(colbase + s * 32 + lc, lut, cq, cqb) + lane * 4);
            bf16x4 h = { f2bf(v[0]), f2bf(v[1]), f2bf(v[2]), f2bf(v[3]) };
            *(bf16x4*)(&lds[lc * LPITCH + lane * 4]) = h;
        }
        __syncthreads();

        #pragma unroll
        for (int st = 0; st < 2; ++st) {
            const int lc = st * 16 + l15;
            f32x4 cc[4];
            #pragma unroll
            for (int q = 0; q < 4; ++q) cc[q] = f32x4{0.f, 0.f, 0.f, 0.f};
            #pragma unroll
            for (int kk = 0; kk < 8; ++kk) {
                const bf16x8 b = *(const bf16x8*)(&lds[lc * LPITCH + kk * 32 + quad * 8]);
                cc[0] = __builtin_amdgcn_mfma_f32_16x16x32_bf16(afrag[0][kk], b, cc[0], 0, 0, 0);
                cc[1] = __builtin_amdgcn_mfma_f32_16x16x32_bf16(afrag[1][kk], b, cc[1], 0, 0, 0);
                cc[2] = __builtin_amdgcn_mfma_f32_16x16x32_bf16(afrag[2][kk], b, cc[2], 0, 0, 0);
                cc[3] = __builtin_amdgcn_mfma_f32_16x16x32_bf16(afrag[3][kk], b, cc[3], 0, 0, 0);
            }
            const int n = colbase + s * 32 + st * 16 + l15;
            const bool okc  = n < NTOT;
            const bool isbg = n < NBG;
            #pragma unroll
            for (int q = 0; q < 4; ++q) {
                #pragma unroll
                for (int r = 0; r < 4; ++r) {
                    float e = exp2f(cc[q][r] * SCALE_LOG2E);
                    e = okc ? e : 0.f;
                    pbg[q * 4 + r] += isbg ? e : 0.f;
                    pnb[q * 4 + r] += isbg ? 0.f : e;
                }
            }
        }
    }

    #pragma unroll
    for (int off = 1; off < 16; off <<= 1) {
        #pragma unroll
        for (int i = 0; i < 16; ++i) {
            pbg[i] += __shfl_xor(pbg[i], off);
            pnb[i] += __shfl_xor(pnb[i], off);
        }
    }
    if (l15 == 0) {
        #pragma unroll
        for (int q = 0; q < 4; ++q) {
            #pragma unroll
            for (int r = 0; r < 4; ++r) {
                const int row = rowbase + wave * 64 + q * 16 + quad * 4 + r;
                atomic_add_f(&sum_bg[row], pbg[q * 4 + r]);
                atomic_add_f(&sum_nb[row], pnb[q * 4 + r]);
            }
        }
    }
}

// -------- Stage 2: finalize (128 blocks; wave = 8 rows) + scalar fold ------
__global__ __launch_bounds__(256) void finalize_kernel(
    const float* __restrict__ inputs, const int* __restrict__ roi_label,
    const float* __restrict__ lut,
    const float* __restrict__ sum_bg, const float* __restrict__ sum_nb,
    float* __restrict__ accums, unsigned int* __restrict__ ticket,
    float* __restrict__ out)
{
    __shared__ float s_det[4], s_oim[4], s_nv[4];
    const int wid  = threadIdx.x >> 6;
    const int lane = threadIdx.x & 63;

    float det_a = 0.f, oim_a = 0.f, nv_a = 0.f;

    #pragma unroll 1
    for (int it = 0; it < 8; ++it) {
        const int row = blockIdx.x * 32 + wid * 8 + it;
        const int r   = roi_label[row];

        float dot = 0.f;
        {
            const int rc = r < 0 ? 0 : r;
            const f32x4 xi = *(const f32x4*)(inputs + (size_t)row * FEAT + lane * 4);
            const f32x4 li = *(const f32x4*)(lut + (size_t)rc * FEAT + lane * 4);
            #pragma unroll
            for (int jj = 0; jj < 4; ++jj) {
                float a = __bfloat162float(__float2bfloat16(xi[jj]));
                float b = __bfloat162float(__float2bfloat16(li[jj]));
                dot += a * b;
            }
        }
        #pragma unroll
        for (int off = 32; off > 0; off >>= 1) dot += __shfl_xor(dot, off);

        if (lane == 0) {
            const float sbg = sum_bg[row];
            const float snb = sum_nb[row];
            const float inv = 1.f / (sbg + snb);
            const float cls0 = sbg * inv;
            const float cls1 = snb * inv;
            out[2 * row]     = cls0;
            out[2 * row + 1] = cls1;

            const float cs = (r >= -1) ? cls1 : cls0;
            const float om = 1.f - cs;
            det_a += -(0.25f * om * om * logf(cs)) * (1.f / (float)BATCH);
            nv_a  += (r >= -1) ? 1.f : 0.f;

            if (r >= 0) {
                const float slab = 30.f * dot;
                const float logp = slab - logf(snb);
                const float p    = expf(logp);
                const float om2  = 1.f - p;
                oim_a += -(0.25f * om2 * om2 * logp) * cls1 * cls1;
            }
        }
    }

    if (lane == 0) { s_det[wid] = det_a; s_oim[wid] = oim_a; s_nv[wid] = nv_a; }
    __syncthreads();
    if (threadIdx.x == 0) {
        atomic_add_f(&accums[0], s_det[0] + s_det[1] + s_det[2] + s_det[3]);
        atomic_add_f(&accums[1], s_oim[0] + s_oim[1] + s_oim[2] + s_oim[3]);
        atomic_add_f(&accums[2], s_nv[0] + s_nv[1] + s_nv[2] + s_nv[3]);
        __threadfence();
        const unsigned t = __hip_atomic_fetch_add(ticket, 1u, __ATOMIC_ACQ_REL,
                                                  __HIP_MEMORY_SCOPE_AGENT);
        if (t == gridDim.x - 1) {
            const float det = __hip_atomic_load(&accums[0], __ATOMIC_RELAXED, __HIP_MEMORY_SCOPE_AGENT);
            const float oim = __hip_atomic_load(&accums[1], __ATOMIC_RELAXED, __HIP_MEMORY_SCOPE_AGENT);
            float nv        = __hip_atomic_load(&accums[2], __ATOMIC_RELAXED, __HIP_MEMORY_SCOPE_AGENT);
            if (nv < 1.f) nv = 1.f;
            out[2 * BATCH]     = det;
            out[2 * BATCH + 1] = oim / nv;
        }
    }
}

extern "C" void kernel_launch(void* const* d_in, const int* in_sizes, int n_in,
                              void* d_out, int out_size, void* d_ws, size_t ws_size,
                              hipStream_t stream)
{
    const float* inputs = (const float*)d_in[0];
    const int*   roi    = (const int*)d_in[1];
    const float* lut    = (const float*)d_in[2];
    const float* cq     = (const float*)d_in[3];
    const float* cqb    = (const float*)d_in[4];
    float* out = (float*)d_out;

    if (ws_size >= (size_t)WS_NEED) {
        u16* tabt = (u16*)d_ws;
        u16* at   = (u16*)((char*)d_ws + TABT_BYTES);
        float* S  = (float*)((char*)d_ws + SUMS_OFF);
        prepass_kernel<<<PRE_BLOCKS, 256, 0, stream>>>(inputs, lut, cq, cqb, tabt, at, S);
        score_bf16_kernel<<<976, 512, 0, stream>>>(tabt, at, S, S + BATCH);
        finalize_kernel<<<128, 256, 0, stream>>>(
            inputs, roi, lut, S, S + BATCH, S + 2 * BATCH,
            (unsigned int*)(S + 2 * BATCH + 3), out);
    } else {
        float* S = (float*)d_ws;
        hipMemsetAsync(S, 0, SUMS_FLOATS * sizeof(float), stream);
        dim3 g1(61, 16);
        score_f32_kernel<<<g1, 256, 0, stream>>>(inputs, lut, cq, cqb, S, S + BATCH);
        finalize_kernel<<<128, 256, 0, stream>>>(
            inputs, roi, lut, S, S + BATCH, S + 2 * BATCH,
            (unsigned int*)(S + 2 * BATCH + 3), out);
    }
}

// Round 10
// 135.757 us; speedup vs baseline: 1.3006x; 1.3006x over previous
//
#include <hip/hip_runtime.h>
#include <hip/hip_bf16.h>

typedef unsigned short u16;
typedef __attribute__((ext_vector_type(8))) short bf16x8;   // 8 bf16 = 4 VGPRs
typedef __attribute__((ext_vector_type(4))) short bf16x4;
typedef __attribute__((ext_vector_type(4))) float f32x4;
typedef __attribute__((ext_vector_type(16))) float f32x16;

#define NBG   5000
#define NPID  5532
#define NTOT  15532      // 5000 + 5532 + 5000
#define FEAT  256
#define BATCH 4096
#define SCALE_LOG2E 43.280851226668994f   // 30 * log2(e)
#define LPITCH 264       // f32-fallback LDS pitch (shorts)

// Padded-column table layout: bg cols [0,5120) hold table rows [0,5000)+pad,
// nb cols [5120,15872) hold table rows [5000,15532)+pad. Every 256-col chunk
// is PURE bg or nb -> single accumulator, no per-step class branching.
#define BGPAD    5120            // 20 chunks
#define TOTPAD   15872           // 62 chunks (42 nb chunks)
#define NCHUNKS  62
#define NTILE_B  992             // TOTPAD / 16
#define TILE_SH  4096            // shorts per 16-col tile (16*256)
#define NTILE_A  256             // 4096 rows / 16
#define STEP_SH  8192            // shorts per 32-col step (2 tiles)
#define NB_LIMIT 15652           // 5120 + 10532: last valid padded col + 1 (nb)

// ---- workspace layout (bytes) ----
#define TABT_BYTES ((size_t)NTILE_B * TILE_SH * 2)   // 8,126,464
#define AT_BYTES   ((size_t)NTILE_A * TILE_SH * 2)   // 2,097,152
#define SUMS_OFF   (TABT_BYTES + AT_BYTES)
// S floats: [0,4096) bg | [4096,8192) nb | 8192 det | 8193 oim | 8194 nv | 8195 ticket
#define SUMS_FLOATS 8196
#define WS_NEED    (SUMS_OFF + SUMS_FLOATS * 4)

// raw v_exp_f32: args are in [-43.3, 43.3] -> no denorm/overflow fixups needed
__device__ __forceinline__ float fexp2(float x) {
#if __has_builtin(__builtin_amdgcn_exp2f)
    return __builtin_amdgcn_exp2f(x);
#else
    return exp2f(x);
#endif
}

__device__ __forceinline__ void atomic_add_f(float* p, float v) {
    __hip_atomic_fetch_add(p, v, __ATOMIC_RELAXED, __HIP_MEMORY_SCOPE_AGENT);
}
__device__ __forceinline__ short f2bf(float f) {
    return (short)__bfloat16_as_ushort(__float2bfloat16(f));
}
// bank-conflict swizzle: q-slot XORed with row/col bits 1..2.
__device__ __forceinline__ int swz(int rc, int q) { return q ^ ((rc >> 1) & 3); }

__device__ __forceinline__ const float* table_row(
    int n, const float* __restrict__ lut, const float* __restrict__ cq,
    const float* __restrict__ cqb)
{
    const int nc = n < NTOT ? n : NTOT - 1;
    if (nc < NBG)        return cqb + (size_t)nc * FEAT;
    if (nc < NBG + NPID) return lut + (size_t)(nc - NBG) * FEAT;
    return cq + (size_t)(nc - NBG - NPID) * FEAT;
}

// -------- Stage 0: f32 -> bf16 tiled prepass (table + inputs) + zero sums --
// Tile format (8192 B per 16-col tile): short off = kk*512 + col*32 + swz(col,q)*8
// holding src[col][kk*32 + q*8 .. +8]. Table rows are PRE-SCALED by 30*log2e.
// Padded col cg maps to source row: cg<BGPAD ? cg (valid cg<NBG)
//                                  : cg-120   (valid cg<NB_LIMIT).
#define TAB_UNITS (NTILE_B * 512)    // 507,904
#define A_UNITS   (NTILE_A * 512)    // 131,072
#define PRE_BLOCKS ((TAB_UNITS + A_UNITS) / 256)   // 2496

__global__ __launch_bounds__(256) void prepass_kernel(
    const float* __restrict__ inputs, const float* __restrict__ lut,
    const float* __restrict__ cq, const float* __restrict__ cqb,
    u16* __restrict__ tabt, u16* __restrict__ at, float* __restrict__ S)
{
    const int u = blockIdx.x * 256 + threadIdx.x;
    if (u < SUMS_FLOATS) S[u] = 0.f;

    if (u < TAB_UNITS) {
        const int tile = u >> 9, v = u & 511;
        const int kk = v >> 6, col = (v >> 2) & 15, q = v & 3;
        const int cg = tile * 16 + col;
        const int srcn  = (cg < BGPAD) ? cg : cg - 120;
        const bool valid = (cg < BGPAD) ? (cg < NBG) : (cg < NB_LIMIT);
        bf16x8 r = {0, 0, 0, 0, 0, 0, 0, 0};
        if (valid) {
            const float* src = table_row(srcn, lut, cq, cqb) + kk * 32 + q * 8;
            const f32x4 lo = *(const f32x4*)src;
            const f32x4 hi = *(const f32x4*)(src + 4);
            r = bf16x8{ f2bf(lo[0] * SCALE_LOG2E), f2bf(lo[1] * SCALE_LOG2E),
                        f2bf(lo[2] * SCALE_LOG2E), f2bf(lo[3] * SCALE_LOG2E),
                        f2bf(hi[0] * SCALE_LOG2E), f2bf(hi[1] * SCALE_LOG2E),
                        f2bf(hi[2] * SCALE_LOG2E), f2bf(hi[3] * SCALE_LOG2E) };
        }
        const size_t off = (size_t)tile * TILE_SH + kk * 512 + col * 32 + swz(col, q) * 8;
        *(bf16x8*)(tabt + off) = r;
    } else {
        const int ua = u - TAB_UNITS;
        const int tile = ua >> 9, v = ua & 511;
        const int kk = v >> 6, row = (v >> 2) & 15, q = v & 3;
        const float* src = inputs + (size_t)(tile * 16 + row) * FEAT + kk * 32 + q * 8;
        const f32x4 lo = *(const f32x4*)src;
        const f32x4 hi = *(const f32x4*)(src + 4);
        bf16x8 r = { f2bf(lo[0]), f2bf(lo[1]), f2bf(lo[2]), f2bf(lo[3]),
                     f2bf(hi[0]), f2bf(hi[1]), f2bf(hi[2]), f2bf(hi[3]) };
        const size_t off = (size_t)tile * TILE_SH + kk * 512 + row * 32 + swz(row, q) * 8;
        *(bf16x8*)(at + off) = r;
    }
}

// -------- Stage 1: fused GEMM + exp-sum, LDS-shared B ----------------------
// 992 blocks (16 rowchunks x 62 colchunks), XCD-swizzled (992 = 8*124,
// bijective). 8 waves x 512 thr, block tile 256x256; wave owns 32 rows via
// v_mfma_f32_32x32x16_bf16 (r8-validated fragment mapping, absmax 0.0039).
// ROUND-10 FIXES vs r8 (which ran at VGPR_Count=64 -> af spilled, A re-read
// from L2 every step, FETCH 61 MB, MfmaUtil 13%):
//   (1) amdgpu_waves_per_eu(4,4) [r9-proven to run] pins 4 waves/SIMD so the
//       allocator gets the full 128-reg budget and keeps af[16] RESIDENT.
//   (2) single p[16] accumulator (-16 VGPRs): every chunk is pure bg or nb
//       under the padded layout; destination array chosen once per block.
// Per-lane masking only on the last step of chunks 19 (bg edge, col<5000)
// and 61 (nb edge, col<15652); chunk 19 runs 5 steps, chunk 61 runs 2.
__global__ __launch_bounds__(512)
__attribute__((amdgpu_waves_per_eu(4, 4)))
void score_bf16_kernel(
    const u16* __restrict__ tabt, const u16* __restrict__ at,
    float* __restrict__ sum_bg, float* __restrict__ sum_nb)
{
    __shared__ __align__(16) short lbuf[2][STEP_SH];
    const int lid = blockIdx.x;
    const int x8  = lid & 7;
    const int j   = lid >> 3;                 // [0, 124)
    const int rowchunk = x8 * 2 + (j & 1);    // [0, 16)
    const int colchunk = j >> 1;              // [0, 62)

    const int tid  = threadIdx.x;             // [0, 512)
    const int wave = tid >> 6;                // [0, 8)
    const int lane = tid & 63;
    const int col5 = lane & 31;               // MFMA col (B) / row (A) selector
    const int half = lane >> 5;               // k-group selector
    const int l15  = lane & 15;
    const int tsel = (lane >> 4) & 1;         // 16-wide tile within 32-col step
    // within-kk-block short offsets for the two q slots this lane uses:
    const int s0 = l15 * 32 + swz(l15, half) * 8;        // ks even: q = half
    const int s1 = l15 * 32 + swz(l15, 2 + half) * 8;    // ks odd:  q = 2+half

    const bool isbg  = colchunk < 20;
    const int  limit = isbg ? NBG : NB_LIMIT; // valid padded-col bound
    const int  steps = (colchunk == 19) ? 5 : (colchunk == 61) ? 2 : 8;
    const int  maskstep = (colchunk == 19 || colchunk == 61) ? steps - 1 : 8;
    const u16* gbase = tabt + (size_t)colchunk * 16 * TILE_SH;

    // stage step t into buf: 512 threads x 32 B = 16 KB. Per wave: two 1 KB
    // DMAs (wave-uniform LDS base + lane*16B; format-preserving linear copy).
    const int stage_off = wave * 512 + lane * 8;      // shorts
    #define STAGE(buf_, t_)                                                    \
        {                                                                      \
            const u16* gs = gbase + (size_t)(t_) * STEP_SH + stage_off;        \
            short* ls = &lbuf[buf_][wave * 512];                               \
            __builtin_amdgcn_global_load_lds(                                  \
                (const __attribute__((address_space(1))) void*)(gs),           \
                (__attribute__((address_space(3))) void*)(ls), 16, 0, 0);      \
            __builtin_amdgcn_global_load_lds(                                  \
                (const __attribute__((address_space(1))) void*)(gs + 4096),    \
                (__attribute__((address_space(3))) void*)(ls + 4096), 16, 0, 0); \
        }

    // issue loads(0) first so they fly during the A-frag prologue
    STAGE(0, 0);

    // A fragments: wave rows [rowchunk*256 + wave*32, +32); lane row = col5.
    bf16x8 af[16];
    {
        const u16* ab = at + (size_t)(rowchunk * 16 + wave * 2 + tsel) * TILE_SH;
        #pragma unroll
        for (int ks = 0; ks < 16; ++ks)
            af[ks] = *(const bf16x8*)(ab + (ks >> 1) * 512 + ((ks & 1) ? s1 : s0));
    }

    float p[16];
    #pragma unroll
    for (int i = 0; i < 16; ++i) p[i] = 0.f;

    #pragma unroll 1
    for (int t = 0; t < steps; ++t) {
        __syncthreads();                       // drains loads(t); all waves synced
        if (t + 1 < steps) STAGE((t + 1) & 1, t + 1);   // prefetch under compute

        const short* lb = lbuf[t & 1] + tsel * TILE_SH;
        f32x16 acc = {};
        __builtin_amdgcn_s_setprio(1);         // T5: favor MFMA-issuing wave
        #pragma unroll
        for (int ks = 0; ks < 16; ++ks) {
            const bf16x8 b = *(const bf16x8*)(lb + (ks >> 1) * 512 + ((ks & 1) ? s1 : s0));
            acc = __builtin_amdgcn_mfma_f32_32x32x16_bf16(af[ks], b, acc, 0, 0, 0);
        }
        __builtin_amdgcn_s_setprio(0);

        if (t == maskstep) {                   // boundary step: mask pad cols
            const bool okc = (colchunk * 256 + t * 32 + col5) < limit;
            #pragma unroll
            for (int i = 0; i < 16; ++i)
                p[i] += okc ? fexp2(acc[i]) : 0.f;
        } else {
            #pragma unroll
            for (int i = 0; i < 16; ++i)
                p[i] += fexp2(acc[i]);
        }
    }

    // reduce across the 32 cols (lanes within each 32-lane group)
    #pragma unroll
    for (int off = 1; off < 32; off <<= 1) {
        #pragma unroll
        for (int i = 0; i < 16; ++i)
            p[i] += __shfl_xor(p[i], off);
    }
    if (col5 == 0) {
        float* dst = isbg ? sum_bg : sum_nb;
        #pragma unroll
        for (int reg = 0; reg < 16; ++reg) {
            const int row = rowchunk * 256 + wave * 32
                          + (reg & 3) + 8 * (reg >> 2) + 4 * half;
            atomic_add_f(&dst[row], p[reg]);
        }
    }
    #undef STAGE
}

// -------- Stage 1 (f32 fallback, round-4 structure, proven) ----------------
__global__ __launch_bounds__(256, 2) void score_f32_kernel(
    const float* __restrict__ inputs, const float* __restrict__ lut,
    const float* __restrict__ cq, const float* __restrict__ cqb,
    float* __restrict__ sum_bg, float* __restrict__ sum_nb)
{
    __shared__ __align__(16) short lds[32 * LPITCH];
    const int wave = threadIdx.x >> 6;
    const int lane = threadIdx.x & 63;
    const int l15  = lane & 15;
    const int quad = lane >> 4;
    const int rowbase = blockIdx.y * 256;
    const int colbase = blockIdx.x * 256;

    bf16x8 afrag[4][8];
    #pragma unroll 1
    for (int c = 0; c < 8; ++c) {
        __syncthreads();
        #pragma unroll
        for (int i = 0; i < 8; ++i) {
            const int lr = i * 4 + wave;
            const f32x4 v = *(const f32x4*)(inputs + (size_t)(rowbase + c * 32 + lr) * FEAT + lane * 4);
            bf16x4 h = { f2bf(v[0]), f2bf(v[1]), f2bf(v[2]), f2bf(v[3]) };
            *(bf16x4*)(&lds[lr * LPITCH + lane * 4]) = h;
        }
        __syncthreads();
        if ((c >> 1) == wave) {
            const int half = c & 1;
            #pragma unroll
            for (int j2 = 0; j2 < 2; ++j2) {
                const int lr = j2 * 16 + l15;
                #pragma unroll
                for (int kk = 0; kk < 8; ++kk)
                    afrag[half * 2 + j2][kk] =
                        *(const bf16x8*)(&lds[lr * LPITCH + kk * 32 + quad * 8]);
            }
        }
    }

    float pbg[16], pnb[16];
    #pragma unroll
    for (int i = 0; i < 16; ++i) { pbg[i] = 0.f; pnb[i] = 0.f; }

    #pragma unroll 1
    for (int s = 0; s < 8; ++s) {
        __syncthreads();
        #pragma unroll
        for (int i = 0; i < 8; ++i) {
            const int lc = i * 4 + wave;
            const f32x4 v = *(const f32x4*)(table_row(colbase + s * 32 + lc, lut, cq, cqb) + lane * 4);
            bf16x4 h = { f2bf(v[0]), f2bf(v[1]), f2bf(v[2]), f2bf(v[3]) };
            *(bf16x4*)(&lds[lc * LPITCH + lane * 4]) = h;
        }
        __syncthreads();

        #pragma unroll
        for (int st = 0; st < 2; ++st) {
            const int lc = st * 16 + l15;
            f32x4 cc[4];
            #pragma unroll
            for (int q = 0; q < 4; ++q) cc[q] = f32x4{0.f, 0.f, 0.f, 0.f};
            #pragma unroll
            for (int kk = 0; kk < 8; ++kk) {
                const bf16x8 b = *(const bf16x8*)(&lds[lc * LPITCH + kk * 32 + quad * 8]);
                cc[0] = __builtin_amdgcn_mfma_f32_16x16x32_bf16(afrag[0][kk], b, cc[0], 0, 0, 0);
                cc[1] = __builtin_amdgcn_mfma_f32_16x16x32_bf16(afrag[1][kk], b, cc[1], 0, 0, 0);
                cc[2] = __builtin_amdgcn_mfma_f32_16x16x32_bf16(afrag[2][kk], b, cc[2], 0, 0, 0);
                cc[3] = __builtin_amdgcn_mfma_f32_16x16x32_bf16(afrag[3][kk], b, cc[3], 0, 0, 0);
            }
            const int n = colbase + s * 32 + st * 16 + l15;
            const bool okc  = n < NTOT;
            const bool isbg = n < NBG;
            #pragma unroll
            for (int q = 0; q < 4; ++q) {
                #pragma unroll
                for (int r = 0; r < 4; ++r) {
                    float e = exp2f(cc[q][r] * SCALE_LOG2E);
                    e = okc ? e : 0.f;
                    pbg[q * 4 + r] += isbg ? e : 0.f;
                    pnb[q * 4 + r] += isbg ? 0.f : e;
                }
            }
        }
    }

    #pragma unroll
    for (int off = 1; off < 16; off <<= 1) {
        #pragma unroll
        for (int i = 0; i < 16; ++i) {
            pbg[i] += __shfl_xor(pbg[i], off);
            pnb[i] += __shfl_xor(pnb[i], off);
        }
    }
    if (l15 == 0) {
        #pragma unroll
        for (int q = 0; q < 4; ++q) {
            #pragma unroll
            for (int r = 0; r < 4; ++r) {
                const int row = rowbase + wave * 64 + q * 16 + quad * 4 + r;
                atomic_add_f(&sum_bg[row], pbg[q * 4 + r]);
                atomic_add_f(&sum_nb[row], pnb[q * 4 + r]);
            }
        }
    }
}

// -------- Stage 2: finalize (128 blocks; wave = 8 rows) + scalar fold ------
__global__ __launch_bounds__(256) void finalize_kernel(
    const float* __restrict__ inputs, const int* __restrict__ roi_label,
    const float* __restrict__ lut,
    const float* __restrict__ sum_bg, const float* __restrict__ sum_nb,
    float* __restrict__ accums, unsigned int* __restrict__ ticket,
    float* __restrict__ out)
{
    __shared__ float s_det[4], s_oim[4], s_nv[4];
    const int wid  = threadIdx.x >> 6;
    const int lane = threadIdx.x & 63;

    float det_a = 0.f, oim_a = 0.f, nv_a = 0.f;

    #pragma unroll 1
    for (int it = 0; it < 8; ++it) {
        const int row = blockIdx.x * 32 + wid * 8 + it;
        const int r   = roi_label[row];

        float dot = 0.f;
        {
            const int rc = r < 0 ? 0 : r;
            const f32x4 xi = *(const f32x4*)(inputs + (size_t)row * FEAT + lane * 4);
            const f32x4 li = *(const f32x4*)(lut + (size_t)rc * FEAT + lane * 4);
            #pragma unroll
            for (int jj = 0; jj < 4; ++jj) {
                float a = __bfloat162float(__float2bfloat16(xi[jj]));
                float b = __bfloat162float(__float2bfloat16(li[jj]));
                dot += a * b;
            }
        }
        #pragma unroll
        for (int off = 32; off > 0; off >>= 1) dot += __shfl_xor(dot, off);

        if (lane == 0) {
            const float sbg = sum_bg[row];
            const float snb = sum_nb[row];
            const float inv = 1.f / (sbg + snb);
            const float cls0 = sbg * inv;
            const float cls1 = snb * inv;
            out[2 * row]     = cls0;
            out[2 * row + 1] = cls1;

            const float cs = (r >= -1) ? cls1 : cls0;
            const float om = 1.f - cs;
            det_a += -(0.25f * om * om * logf(cs)) * (1.f / (float)BATCH);
            nv_a  += (r >= -1) ? 1.f : 0.f;

            if (r >= 0) {
                const float slab = 30.f * dot;
                const float logp = slab - logf(snb);
                const float p    = expf(logp);
                const float om2  = 1.f - p;
                oim_a += -(0.25f * om2 * om2 * logp) * cls1 * cls1;
            }
        }
    }

    if (lane == 0) { s_det[wid] = det_a; s_oim[wid] = oim_a; s_nv[wid] = nv_a; }
    __syncthreads();
    if (threadIdx.x == 0) {
        atomic_add_f(&accums[0], s_det[0] + s_det[1] + s_det[2] + s_det[3]);
        atomic_add_f(&accums[1], s_oim[0] + s_oim[1] + s_oim[2] + s_oim[3]);
        atomic_add_f(&accums[2], s_nv[0] + s_nv[1] + s_nv[2] + s_nv[3]);
        __threadfence();
        const unsigned t = __hip_atomic_fetch_add(ticket, 1u, __ATOMIC_ACQ_REL,
                                                  __HIP_MEMORY_SCOPE_AGENT);
        if (t == gridDim.x - 1) {
            const float det = __hip_atomic_load(&accums[0], __ATOMIC_RELAXED, __HIP_MEMORY_SCOPE_AGENT);
            const float oim = __hip_atomic_load(&accums[1], __ATOMIC_RELAXED, __HIP_MEMORY_SCOPE_AGENT);
            float nv        = __hip_atomic_load(&accums[2], __ATOMIC_RELAXED, __HIP_MEMORY_SCOPE_AGENT);
            if (nv < 1.f) nv = 1.f;
            out[2 * BATCH]     = det;
            out[2 * BATCH + 1] = oim / nv;
        }
    }
}

extern "C" void kernel_launch(void* const* d_in, const int* in_sizes, int n_in,
                              void* d_out, int out_size, void* d_ws, size_t ws_size,
                              hipStream_t stream)
{
    const float* inputs = (const float*)d_in[0];
    const int*   roi    = (const int*)d_in[1];
    const float* lut    = (const float*)d_in[2];
    const float* cq     = (const float*)d_in[3];
    const float* cqb    = (const float*)d_in[4];
    float* out = (float*)d_out;

    if (ws_size >= (size_t)WS_NEED) {
        u16* tabt = (u16*)d_ws;
        u16* at   = (u16*)((char*)d_ws + TABT_BYTES);
        float* S  = (float*)((char*)d_ws + SUMS_OFF);
        prepass_kernel<<<PRE_BLOCKS, 256, 0, stream>>>(inputs, lut, cq, cqb, tabt, at, S);
        score_bf16_kernel<<<992, 512, 0, stream>>>(tabt, at, S, S + BATCH);
        finalize_kernel<<<128, 256, 0, stream>>>(
            inputs, roi, lut, S, S + BATCH, S + 2 * BATCH,
            (unsigned int*)(S + 2 * BATCH + 3), out);
    } else {
        float* S = (float*)d_ws;
        hipMemsetAsync(S, 0, SUMS_FLOATS * sizeof(float), stream);
        dim3 g1(61, 16);
        score_f32_kernel<<<g1, 256, 0, stream>>>(inputs, lut, cq, cqb, S, S + BATCH);
        finalize_kernel<<<128, 256, 0, stream>>>(
            inputs, roi, lut, S, S + BATCH, S + 2 * BATCH,
            (unsigned int*)(S + 2 * BATCH + 3), out);
    }
}